// Round 10
// baseline (134.220 us; speedup 1.0000x reference)
//
#include <hip/hip_runtime.h>
#include <hip/hip_bf16.h>
#include <math.h>

// Problem constants (from reference)
#define BB 4
#define NN 256
#define FF 256
#define NF 192
#define MTOT 262144.0f               // B*N*N samples per channel for BN stats
#define NB2 2560                     // triangular quarter-blocks per GEMM pass (4b x 640)

typedef unsigned short u16;
typedef unsigned int   u32;
typedef __attribute__((ext_vector_type(8))) short bf16x8;  // 8 bf16 = 4 VGPRs (MFMA A/B frag)
typedef __attribute__((ext_vector_type(4))) float f32x4;   // MFMA C/D frag

// ---- workspace layout (bytes) ----
#define W1P_OFF 0                    // w1 packed bf16 [fc(32)][c(192)][8]: 98304 B
#define AD_OFF  98304                // per-channel {A,D} float2: 1536 B
#define P_OFF   99840                // partials: S at [c][NB2], Q at [192+c][NB2]: 3.93 MB
// total ws: ~4.03 MB

__device__ __forceinline__ u32 pk2(float a, float b) {
    u32 r;
    asm("v_cvt_pk_bf16_f32 %0, %1, %2" : "=v"(r) : "v"(a), "v"(b));
    return r;  // low16 = bf16(a), high16 = bf16(b)
}

__device__ __forceinline__ u16 f2bf(float f) {  // RNE, cold path only
    u32 u = __float_as_uint(f);
    return (u16)((u + 0x7FFFu + ((u >> 16) & 1u)) >> 16);
}

// ---- K0: pack w1 [F][NF] fp32 -> bf16 blocks [fc][c][e], f = fc*8+e ----
__global__ void k0_pack_w1(const float* __restrict__ w1, u16* __restrict__ w1p) {
    int idx = blockIdx.x * 256 + threadIdx.x;        // 0..49151
    int e  = idx & 7;
    int c  = (idx >> 3) % NF;
    int fc = idx / (NF * 8);
    w1p[idx] = f2bf(w1[(fc * 8 + e) * NF + c]);
}

// ---- blockIdx -> (b, i, qj) for the triangular quarter grid ----
// per b: 640 pairs, segments by qi: [0,256):qi=0, [256,448):1, [448,576):2, [576,640):3
__device__ __forceinline__ void block_map(int bid, int& b, int& i, int& qj) {
    b = bid / 640;
    int r = bid % 640;
    int q, rr;
    if      (r < 256) { q = 0; rr = r; }
    else if (r < 448) { q = 1; rr = r - 256; }
    else if (r < 576) { q = 2; rr = r - 448; }
    else              { q = 3; rr = r - 576; }
    const int per = 4 - q;
    i  = q * 64 + rr / per;
    qj = q + rr % per;
}

// =====================================================================
// GEMM core: block = (b, i, qj); 256 threads = 4 waves.
// Output tile: 64 j x 192 c; wave tile 32j x 96c -> 12 acc frags.
// K=256 in 4 PHASES of BK=64 (was 8 of 32) -> 24 MFMA/phase (~470
// SIMD-cyc) covers the per-phase staging chain (x L2 load ~250cy +
// diff VALU + ds_write + barrier), and barrier count halves.
// [round-8 post-mortem: B-frag L2 prefetch gained only ~5us -> per-slice
// load latency was not the stall; phase cadence is the next suspect.]
// diff tile: [64 rows][8 uint4 chunks] (128B row), dbuf = 16KB LDS.
// Swizzle chunk ^= (row&7): ds_write_b128 (4thr/row, 2 chunks) and
// ds_read_b128 (16 rows @ fixed chunk) both cover all 8 bank-groups per
// 8-lane phase (slot-enumerated, conflict-free). B-frags: in-place
// reload after last use, one k=32 sub-slice ahead (register-neutral).
// WAR-hazard proof: end-of-phase-kk staging writes buf[(kk+1)&1], whose
// last reads (phase kk-1) are lgkm-drained at the phase-kk barrier.
// Fragment maps HW-validated in round 3.
// =====================================================================
__device__ __forceinline__ void gemm_core(const float* __restrict__ x,
        const u16* __restrict__ w1p, int b, int i, int qj, int t,
        float* sxi, uint4* sd, f32x4 acc[2][6]) {
    const int l = t & 63, l15 = l & 15, lg = l >> 4, w = t >> 6;
    const int jw = (w >> 1) * 32;          // wave j-chunk (2 x 32)
    const int cw = (w & 1) * 96;           // wave c-chunk (2 x 96)
    const int jrow = t >> 2;               // staging row 0..63
    const int c0 = (t & 3) * 2;            // staging chunks c0, c0+1
    const int jglob = qj * 64 + jrow;
    const float* xpt = x + (size_t)(b * NN + jglob) * FF + c0 * 8;  // 4 float4 from here
    const int w0 = jrow * 8 + ((c0)     ^ (jrow & 7));
    const int w1i = jrow * 8 + ((c0 + 1) ^ (jrow & 7));
    int aidx[2][2];                        // [ks][a]
    #pragma unroll
    for (int a = 0; a < 2; a++) {
        const int row = jw + a * 16 + l15;
        #pragma unroll
        for (int ks = 0; ks < 2; ks++)
            aidx[ks][a] = row * 8 + ((ks * 4 + lg) ^ (row & 7));
    }
    const int bbase = lg * NF + cw + l15;
    const bf16x8* w1p8 = (const bf16x8*)w1p;

    sxi[t] = x[(size_t)(b * NN + i) * FF + t];
    // phase-0 x: 4 contiguous float4 (chunks c0, c0+1)
    float4 xa0 = *(const float4*)(xpt);
    float4 xa1 = *(const float4*)(xpt + 4);
    float4 xb0 = *(const float4*)(xpt + 8);
    float4 xb1 = *(const float4*)(xpt + 12);
    bf16x8 bcur[6];                        // sub-slice 0 B-frags, issued pre-barrier
    #pragma unroll
    for (int n = 0; n < 6; n++) bcur[n] = w1p8[bbase + n * 16];
    __syncthreads();                       // sxi ready
    {   // stage phase 0 -> sd[0]
        const float* sx = sxi + c0 * 8;
        uint4 v0, v1;
        v0.x = pk2(fabsf(xa0.x - sx[0]),  fabsf(xa0.y - sx[1]));
        v0.y = pk2(fabsf(xa0.z - sx[2]),  fabsf(xa0.w - sx[3]));
        v0.z = pk2(fabsf(xa1.x - sx[4]),  fabsf(xa1.y - sx[5]));
        v0.w = pk2(fabsf(xa1.z - sx[6]),  fabsf(xa1.w - sx[7]));
        v1.x = pk2(fabsf(xb0.x - sx[8]),  fabsf(xb0.y - sx[9]));
        v1.y = pk2(fabsf(xb0.z - sx[10]), fabsf(xb0.w - sx[11]));
        v1.z = pk2(fabsf(xb1.x - sx[12]), fabsf(xb1.y - sx[13]));
        v1.w = pk2(fabsf(xb1.z - sx[14]), fabsf(xb1.w - sx[15]));
        sd[w0] = v0; sd[w1i] = v1;
    }

    #pragma unroll
    for (int a = 0; a < 2; a++)
        #pragma unroll
        for (int n = 0; n < 6; n++) acc[a][n] = (f32x4){0.f, 0.f, 0.f, 0.f};

    for (int kk = 0; kk < 4; ++kk) {       // 4 phases of BK=64
        __syncthreads();                   // sd[kk&1] ready
        if (kk < 3) {                      // x prefetch for next phase
            const float* xp = xpt + (kk + 1) * 64;
            xa0 = *(const float4*)(xp);
            xa1 = *(const float4*)(xp + 4);
            xb0 = *(const float4*)(xp + 8);
            xb1 = *(const float4*)(xp + 12);
        }
        const int rb = (kk & 1) * 512;
        bf16x8 af[2][2];
        #pragma unroll
        for (int ks = 0; ks < 2; ks++)
            #pragma unroll
            for (int a = 0; a < 2; a++)
                af[ks][a] = *(const bf16x8*)&sd[rb + aidx[ks][a]];
        #pragma unroll
        for (int ks = 0; ks < 2; ks++) {
            const int s = kk * 2 + ks;     // k=32 sub-slice index 0..7
            #pragma unroll
            for (int n = 0; n < 6; n++) {
                acc[0][n] = __builtin_amdgcn_mfma_f32_16x16x32_bf16(af[ks][0], bcur[n], acc[0][n], 0, 0, 0);
                acc[1][n] = __builtin_amdgcn_mfma_f32_16x16x32_bf16(af[ks][1], bcur[n], acc[1][n], 0, 0, 0);
                if (s < 7)                 // slot dead after the 2 MFMAs -> free reload
                    bcur[n] = w1p8[(s + 1) * 768 + bbase + n * 16];
            }
        }
        if (kk < 3) {                      // stage next phase -> sd[(kk+1)&1]
            const int wb = ((kk + 1) & 1) * 512;
            const float* sx = sxi + (kk + 1) * 64 + c0 * 8;
            uint4 v0, v1;
            v0.x = pk2(fabsf(xa0.x - sx[0]),  fabsf(xa0.y - sx[1]));
            v0.y = pk2(fabsf(xa0.z - sx[2]),  fabsf(xa0.w - sx[3]));
            v0.z = pk2(fabsf(xa1.x - sx[4]),  fabsf(xa1.y - sx[5]));
            v0.w = pk2(fabsf(xa1.z - sx[6]),  fabsf(xa1.w - sx[7]));
            v1.x = pk2(fabsf(xb0.x - sx[8]),  fabsf(xb0.y - sx[9]));
            v1.y = pk2(fabsf(xb0.z - sx[10]), fabsf(xb0.w - sx[11]));
            v1.z = pk2(fabsf(xb1.x - sx[12]), fabsf(xb1.y - sx[13]));
            v1.w = pk2(fabsf(xb1.z - sx[14]), fabsf(xb1.w - sx[15]));
            sd[wb + w0] = v0; sd[wb + w1i] = v1;
        }
    }
}

// ---- K1a: triangular GEMM -> weighted per-channel sum/sumsq partials ----
__global__ __launch_bounds__(256, 4) void k1a_stats_gemm(
    const float* __restrict__ x, const u16* __restrict__ w1p,
    float* __restrict__ partials) {

    __shared__ float sxi[FF];              // 1 KB
    __shared__ uint4 sd[2 * 512];          // 16 KB dbuf diff tile (BK=64)
    __shared__ float sstat[4][96][2];      // 3 KB

    int b, i, qj;
    block_map(blockIdx.x, b, i, qj);
    const int t = threadIdx.x;
    const int l = t & 63, l15 = l & 15, w = t >> 6;

    f32x4 acc[2][6];
    gemm_core(x, w1p, b, i, qj, t, sxi, sd, acc);

    // lane: j = jw + a*16 + (l>>4)*4 + r, c = cw + n*16 + l15 (HW-validated map)
    float ps[6], pq[6];
    #pragma unroll
    for (int n = 0; n < 6; n++) {
        float s = 0.f, q = 0.f;
        #pragma unroll
        for (int a = 0; a < 2; a++) {
            const f32x4 v = acc[a][n];
            s += v.x + v.y + v.z + v.w;
            q += v.x * v.x + v.y * v.y + v.z * v.z + v.w * v.w;
        }
        s += __shfl_xor(s, 16); s += __shfl_xor(s, 32);   // sum over lg (j sub-rows)
        q += __shfl_xor(q, 16); q += __shfl_xor(q, 32);
        ps[n] = s; pq[n] = q;
    }
    if (l < 16) {
        #pragma unroll
        for (int n = 0; n < 6; n++) {
            sstat[w][n * 16 + l15][0] = ps[n];
            sstat[w][n * 16 + l15][1] = pq[n];
        }
    }
    __syncthreads();
    if (t < NF) {
        const int ch = t / 96, cl = t % 96;               // waves {ch, ch+2} hold half ch
        float S = sstat[ch][cl][0] + sstat[ch + 2][cl][0];
        float Q = sstat[ch][cl][1] + sstat[ch + 2][cl][1];
        const float W = (qj > (i >> 6)) ? 2.0f : 1.0f;    // mirror weight (diag quarter = 1)
        partials[(size_t)t * NB2 + blockIdx.x]        = S * W;
        partials[(size_t)(NF + t) * NB2 + blockIdx.x] = Q * W;
    }
}

// ---- K2: reduce partials -> A = gamma*rsqrt(var+eps), D = beta - mean*A ----
__global__ void k2_stats(const float* __restrict__ partials,
                         const float* __restrict__ gamma, const float* __restrict__ beta,
                         float2* __restrict__ ad) {
    __shared__ float red[4][2];
    const int c = blockIdx.x;
    const int t = threadIdx.x;
    float S = 0.f, Q = 0.f;
    #pragma unroll
    for (int r = 0; r < 10; ++r) {
        const int blk = t + r * 256;                      // 10*256 = 2560 = NB2
        S += partials[(size_t)c * NB2 + blk];
        Q += partials[(size_t)(NF + c) * NB2 + blk];
    }
    #pragma unroll
    for (int off = 1; off < 64; off <<= 1) { S += __shfl_xor(S, off); Q += __shfl_xor(Q, off); }
    if ((t & 63) == 0) { red[t >> 6][0] = S; red[t >> 6][1] = Q; }
    __syncthreads();
    if (t == 0) {
        S = red[0][0] + red[1][0] + red[2][0] + red[3][0];
        Q = red[0][1] + red[1][1] + red[2][1] + red[3][1];
        const float mean = S / MTOT;
        const float var  = Q / MTOT - mean * mean;
        const float rs   = 1.0f / sqrtf(var + 1e-5f);
        const float A = gamma[c] * rs;
        const float D = beta[c] - mean * A;
        ad[c] = make_float2(A, D);
    }
}

// ---- K1b: triangular GEMM -> BN -> lrelu -> w2 -> raw scores (+mirror) ----
// scores staged in d_out; k3 rewrites in place.
__global__ __launch_bounds__(256, 4) void k1b_score_gemm(
    const float* __restrict__ x, const u16* __restrict__ w1p,
    const float2* __restrict__ ad, const float* __restrict__ w2,
    float* __restrict__ out) {

    __shared__ float sxi[FF];
    __shared__ uint4 sd[2 * 512];
    __shared__ float sA[NF], sD[NF], sW2[NF];
    __shared__ float sS[2][64];

    int b, i, qj;
    block_map(blockIdx.x, b, i, qj);
    const int t = threadIdx.x;
    const int l = t & 63, l15 = l & 15, lg = l >> 4, w = t >> 6;
    const int jw = (w >> 1) * 32, cw = (w & 1) * 96;

    if (t < NF) {
        const float2 v = ad[t];
        sA[t] = v.x; sD[t] = v.y; sW2[t] = w2[t];
    }

    f32x4 acc[2][6];
    gemm_core(x, w1p, b, i, qj, t, sxi, sd, acc);   // its first barrier covers sA/sD/sW2 too

    // epilogue: BN + leaky-relu + w2 contraction, in-register
    float sj[2][4];
    #pragma unroll
    for (int a = 0; a < 2; a++)
        #pragma unroll
        for (int r = 0; r < 4; r++) sj[a][r] = 0.f;
    #pragma unroll
    for (int n = 0; n < 6; n++) {
        const int c = cw + n * 16 + l15;
        const float A = sA[c], D = sD[c], W = sW2[c];
        #pragma unroll
        for (int a = 0; a < 2; a++) {
            const f32x4 v = acc[a][n];
            float z;
            z = fmaf(v.x, A, D); sj[a][0] += fmaxf(z, 0.01f * z) * W;
            z = fmaf(v.y, A, D); sj[a][1] += fmaxf(z, 0.01f * z) * W;
            z = fmaf(v.z, A, D); sj[a][2] += fmaxf(z, 0.01f * z) * W;
            z = fmaf(v.w, A, D); sj[a][3] += fmaxf(z, 0.01f * z) * W;
        }
    }
    #pragma unroll
    for (int a = 0; a < 2; a++)
        #pragma unroll
        for (int r = 0; r < 4; r++) {
            float v = sj[a][r];
            v += __shfl_xor(v, 1); v += __shfl_xor(v, 2);   // sum over 16 c-lanes
            v += __shfl_xor(v, 4); v += __shfl_xor(v, 8);
            if (l15 == 0) sS[w & 1][jw + a * 16 + (lg << 2) + r] = v;
        }
    __syncthreads();

    if (t < 64) {
        const float s = sS[0][t] + sS[1][t];
        const int jglob = qj * 64 + t;
        out[(size_t)(b * NN + i) * NN + jglob] = s;
        if (qj > (i >> 6))                                  // mirror (exactly-once coverage proven)
            out[(size_t)(b * NN + jglob) * NN + i] = s;
    }
}

// ---- K3: in-place row softmax on scores; out = eye - softmax ----
__global__ __launch_bounds__(256) void k3_softmax(float* __restrict__ out) {
    __shared__ float redA[4], redB[4];
    const int r = blockIdx.x, t = threadIdx.x, i = r & 255;
    float s = out[(size_t)r * NN + t];
    if (t == i) s -= 1e8f;                 // self-edge mask (ref semantics)
    float m = s;
    #pragma unroll
    for (int off = 1; off < 64; off <<= 1) m = fmaxf(m, __shfl_xor(m, off));
    if ((t & 63) == 0) redA[t >> 6] = m;
    __syncthreads();
    m = fmaxf(fmaxf(redA[0], redA[1]), fmaxf(redA[2], redA[3]));
    const float e = expf(s - m);           // exp(-1e8 - m) underflows to exact 0
    float q = e;
    #pragma unroll
    for (int off = 1; off < 64; off <<= 1) q += __shfl_xor(q, off);
    if ((t & 63) == 0) redB[t >> 6] = q;
    __syncthreads();
    const float inv = 1.0f / (redB[0] + redB[1] + redB[2] + redB[3]);
    out[(size_t)r * NN + t] = (t == i ? 1.0f : 0.0f) - e * inv;
}

extern "C" void kernel_launch(void* const* d_in, const int* in_sizes, int n_in,
                              void* d_out, int out_size, void* d_ws, size_t ws_size,
                              hipStream_t stream) {
    const float* x     = (const float*)d_in[0];
    // d_in[1] = W_id (identity by construction) -- unused
    const float* w1    = (const float*)d_in[2];
    // d_in[3] = b1 -- cancels in BN mean subtraction; unused
    const float* gamma = (const float*)d_in[4];
    const float* beta  = (const float*)d_in[5];
    const float* w2    = (const float*)d_in[6];
    // d_in[7] = b2 -- cancels in row softmax; unused

    char* ws = (char*)d_ws;
    u16*    w1p      = (u16*)(ws + W1P_OFF);
    float2* ad       = (float2*)(ws + AD_OFF);
    float*  partials = (float*)(ws + P_OFF);
    float*  out      = (float*)d_out;

    k0_pack_w1    <<<dim3(192),  dim3(256), 0, stream>>>(w1, w1p);
    k1a_stats_gemm<<<dim3(NB2),  dim3(256), 0, stream>>>(x, w1p, partials);
    k2_stats      <<<dim3(NF),   dim3(256), 0, stream>>>(partials, gamma, beta, ad);
    k1b_score_gemm<<<dim3(NB2),  dim3(256), 0, stream>>>(x, w1p, ad, w2, out);
    k3_softmax    <<<dim3(BB*NN), dim3(256), 0, stream>>>(out);
}